// Round 2
// baseline (644.776 us; speedup 1.0000x reference)
//
#include <hip/hip_runtime.h>

// RWKV WKV forward scan — single-pass decoupled-lookback chunked scan.
// B=16, T=2048, D=1024, fp32.
//
// Recurrence per (b,d) chain:  a = e^w·a + e^k ; b = e^w·b + e^k·v ; out = b/a.
// Affine in state => associative chunk composition (P, A, B):
//   apply chunk to state x: x' = P·x + (A,B), compose (2∘1) = (P1P2, P2A1+A2, P2B1+B2).
//
// Decomposition: 256 chain-tiles (64 channels each) × 16 superchunks of 128 t.
// Block = 256 threads = (64 ch) × (4 sub-chunks × 32 t). Each thread stashes
// e^w, e^k, e^k·v for its 32 steps in registers (single read of inputs),
// combines sub-chunks via LDS, superchunks via device-scope lookback in d_ws,
// then replays from the corrected initial state. Ticket ordering prevents
// lookback deadlock under partial residency.

#define T_LEN 2048
#define D_LEN 1024
#define B_SZ  16
#define LSTEP 32                         // t-steps stashed per thread
#define UCH   4                          // sub-chunks per block (threadIdx.y)
#define SUPER (T_LEN / (LSTEP * UCH))    // 16 superchunks per chain
#define NTILE (B_SZ * D_LEN / 64)        // 256 chain-tiles
#define NBLK  (NTILE * SUPER)            // 4096 blocks

static_assert(NTILE == 256, "ticket decode assumes NTILE=256");

__global__ __launch_bounds__(256, 4) void wkv_scan(const float* __restrict__ kg,
                                                   const float* __restrict__ vg,
                                                   const float* __restrict__ wg,
                                                   float* __restrict__ og,
                                                   unsigned* __restrict__ counter,
                                                   unsigned* __restrict__ flags,
                                                   float* __restrict__ inc) {
    __shared__ unsigned s_ticket;
    __shared__ float s_part[UCH][3][64];   // per-sub-chunk (P,A,B) per channel
    __shared__ float s_in[3][64];          // incoming state-transform from lookback

    const int ch = threadIdx.x;            // 0..63 channel lane within tile
    const int u  = threadIdx.y;            // 0..3 sub-chunk (== wave id)

    if (ch == 0 && u == 0) s_ticket = atomicAdd(counter, 1u);
    __syncthreads();
    const unsigned ticket = s_ticket;
    const int tile = (int)(ticket & (NTILE - 1));
    const int s    = (int)(ticket >> 8);   // superchunk index, 0..SUPER-1

    const int chain = tile * 64 + ch;                 // 0..16383
    const int bidx  = chain >> 10;                    // / D_LEN
    const int d     = chain & (D_LEN - 1);
    const int t0    = s * (LSTEP * UCH) + u * LSTEP;
    const size_t base = (size_t)bidx * T_LEN * D_LEN + (size_t)t0 * D_LEN + d;

    // ---- phase 1: single read of inputs, stash transforms, local (P,A,B) ----
    float ew[LSTEP], ek[LSTEP], ekv[LSTEP];
    float P = 1.0f, A = 0.0f, Bb = 0.0f;
#pragma unroll
    for (int j = 0; j < LSTEP; ++j) {
        const size_t off = base + (size_t)j * D_LEN;
        const float kj = kg[off];
        const float vj = vg[off];
        const float wj = wg[off];
        const float e1 = __expf(wj);
        const float e2 = __expf(kj);
        ew[j]  = e1;
        ek[j]  = e2;
        ekv[j] = e2 * vj;
        P *= e1;
        A  = e1 * A  + e2;
        Bb = e1 * Bb + ekv[j];
    }

    s_part[u][0][ch] = P;
    s_part[u][1][ch] = A;
    s_part[u][2][ch] = Bb;
    __syncthreads();

    // ---- phase 2: wave 0 does block combine + decoupled lookback ----
    if (u == 0) {
        // block-full partial (compose sub-chunks 0..3)
        float Pf = s_part[0][0][ch], Af = s_part[0][1][ch], Bf = s_part[0][2][ch];
#pragma unroll
        for (int q = 1; q < UCH; ++q) {
            const float Pq = s_part[q][0][ch];
            const float Aq = s_part[q][1][ch];
            const float Bq = s_part[q][2][ch];
            Af = Pq * Af + Aq;
            Bf = Pq * Bf + Bq;
            Pf = Pf * Pq;
        }

        float Pin = 1.0f, Ain = 0.0f, Bin = 0.0f;
        if (s > 0) {
            const int fidx = tile * SUPER + (s - 1);
            // all 64 lanes spin on the same flag (per-lane acquire semantics)
            while (__hip_atomic_load(&flags[fidx], __ATOMIC_ACQUIRE,
                                     __HIP_MEMORY_SCOPE_AGENT) == 0u) {
                __builtin_amdgcn_s_sleep(2);
            }
            const size_t ib = (size_t)fidx * 192;
            Pin = inc[ib + 0 * 64 + ch];
            Ain = inc[ib + 1 * 64 + ch];
            Bin = inc[ib + 2 * 64 + ch];
        }

        // inclusive = incoming then block
        if (s < SUPER - 1) {
            const int   oidx = tile * SUPER + s;
            const size_t ob  = (size_t)oidx * 192;
            inc[ob + 0 * 64 + ch] = Pin * Pf;
            inc[ob + 1 * 64 + ch] = Pf * Ain + Af;
            inc[ob + 2 * 64 + ch] = Pf * Bin + Bf;
            // release publishes the payload stores above (waitcnt drains wave-wide)
            __hip_atomic_store(&flags[oidx], 1u, __ATOMIC_RELEASE,
                               __HIP_MEMORY_SCOPE_AGENT);
        }

        s_in[0][ch] = Pin;
        s_in[1][ch] = Ain;
        s_in[2][ch] = Bin;
    }
    __syncthreads();

    // ---- phase 3: start state = incoming ∘ sub-chunk prefix, replay, write ----
    float Ai = s_in[1][ch], Bi = s_in[2][ch];
#pragma unroll
    for (int q = 0; q < UCH - 1; ++q) {
        if (q < u) {   // wave-uniform branch (u constant per wave)
            const float Pq = s_part[q][0][ch];
            Ai = Pq * Ai + s_part[q][1][ch];
            Bi = Pq * Bi + s_part[q][2][ch];
        }
    }

    float a = Ai, b = Bi;
#pragma unroll
    for (int j = 0; j < LSTEP; ++j) {
        a = ew[j] * a + ek[j];
        b = ew[j] * b + ekv[j];
        og[base + (size_t)j * D_LEN] = __fdividef(b, a);
    }
}

extern "C" void kernel_launch(void* const* d_in, const int* in_sizes, int n_in,
                              void* d_out, int out_size, void* d_ws, size_t ws_size,
                              hipStream_t stream) {
    const float* k = (const float*)d_in[0];
    const float* v = (const float*)d_in[1];
    const float* w = (const float*)d_in[2];
    float* out = (float*)d_out;

    // workspace layout: [0,4)   ticket counter
    //                   [256, 256+16K)   flags  (NBLK uints)
    //                   [256+16K, +3MB)  inc payload (NBLK * 192 floats)
    unsigned* counter = (unsigned*)d_ws;
    unsigned* flags   = (unsigned*)((char*)d_ws + 256);
    float*    inc     = (float*)((char*)d_ws + 256 + NBLK * sizeof(unsigned));

    // zero counter + flags (d_ws is poisoned 0xAA before every launch)
    hipMemsetAsync(d_ws, 0, 256 + NBLK * sizeof(unsigned), stream);

    wkv_scan<<<dim3(NBLK), dim3(64, UCH), 0, stream>>>(k, v, w, out,
                                                       counter, flags, inc);
}